// Round 4
// baseline (373.558 us; speedup 1.0000x reference)
//
#include <hip/hip_runtime.h>

#define SEQ 5000
#define BATCH 64
#define DIM 128
#define PB 16   // blocks per batch
#define TPB 512

// Fused: per block, (1) Wyllie pointer-doubling list ranking of this batch's
// successor cycle in LDS: word = (dist<<16)|next, cycle broken at node 0
// (dist=0,next=0). After 13 doublings (2^13=8192>5000) dist[i] = #steps i->0,
// visited_time = SEQ - dist, idx = (dist==0) ? 0 : vt.  (2) emit this block's
// 1/PB slice of rows: NFE = x@W^T (f32, W in regs), PFE = float4 copy of
// pattern[idx], vt = (float)visited_time.  ALL I/O is float32.
__global__ __launch_bounds__(TPB) void fused_kernel(
    const float2* __restrict__ x,   // [B*S] rows of 2 f32
    const float4* __restrict__ W,   // [128][2] f32 = 64 float4
    const float4* __restrict__ pat, // [S][128] f32: row = 32 float4
    const int* __restrict__ sol,    // [B][S] int32
    float* __restrict__ out) {
    __shared__ unsigned buf[2][SEQ];  // 40 KB
    const int b  = blockIdx.x / PB;
    const int bi = blockIdx.x % PB;

    const int* sp = sol + b * SEQ;
    for (int i = threadIdx.x; i < SEQ; i += TPB) {
        unsigned nx = (unsigned)sp[i];
        if (nx >= SEQ) nx = 0;  // safety: never triggers on valid input
        buf[0][i] = (i == 0) ? 0u : ((1u << 16) | nx);
    }
    __syncthreads();
    int cur = 0;
#pragma unroll 1
    for (int it = 0; it < 13; ++it) {
        for (int i = threadIdx.x; i < SEQ; i += TPB) {
            unsigned w  = buf[cur][i];
            unsigned w2 = buf[cur][w & 0xFFFFu];
            buf[cur ^ 1][i] = (w & 0xFFFF0000u) + w2;  // low 16 can't carry
        }
        __syncthreads();
        cur ^= 1;
    }

    // Output (all f32): [NFE 40.96M | PFE 40.96M | vt 320K]
    const size_t NFE = (size_t)BATCH * SEQ * DIM;
    float4* nfe4 = (float4*)out;
    float4* pfe4 = (float4*)(out + NFE);
    float*  vt_out = out + 2 * NFE;

    const int c = threadIdx.x & 31;  // channel group: d = 4c..4c+3
    // W[d][0..1] for d=4c..4c+3: float4 pairs (w even rows / odd parts)
    float4 wa = W[c * 2 + 0];  // W[4c][0], W[4c][1], W[4c+1][0], W[4c+1][1]
    float4 wb = W[c * 2 + 1];  // W[4c+2][0], W[4c+2][1], W[4c+3][0], W[4c+3][1]

    const int lo = (bi * SEQ) / PB, hi = ((bi + 1) * SEQ) / PB;
    for (int s = lo + (threadIdx.x >> 5); s < hi; s += TPB / 32) {
        unsigned dist = buf[cur][s] >> 16;
        int vt = SEQ - (int)dist;       // 1..5000; node 0 gets 5000
        int i = (dist == 0u) ? 0 : vt;  // vt % SEQ
        if ((unsigned)i >= SEQ) i = 0;  // safety clamp
        const size_t r = (size_t)b * SEQ + s;

        float2 xv = x[r];
        float4 nv;
        nv.x = fmaf(xv.x, wa.x, xv.y * wa.y);
        nv.y = fmaf(xv.x, wa.z, xv.y * wa.w);
        nv.z = fmaf(xv.x, wb.x, xv.y * wb.y);
        nv.w = fmaf(xv.x, wb.z, xv.y * wb.w);
        nfe4[r * 32 + c] = nv;

        pfe4[r * 32 + c] = pat[(size_t)i * 32 + c];  // bit-exact gather

        if (c == 0) vt_out[r] = (float)vt;
    }
}

extern "C" void kernel_launch(void* const* d_in, const int* in_sizes, int n_in,
                              void* d_out, int out_size, void* d_ws, size_t ws_size,
                              hipStream_t stream) {
    // setup_inputs() dict order: x, W, pattern, solutions (all f32 / int32).
    const void* xp = d_in[0];  // f32 [64,5000,2]
    const void* wp = d_in[1];  // f32 [128,2]
    const void* pp = d_in[2];  // f32 [5000,128]
    const void* sp = d_in[3];  // int32 [64,5000]
    // Defensive remap by element count (W=256, sol=320000; the two 640000s
    // keep relative order: x first, pattern second).
    {
        const void* big[2] = {nullptr, nullptr};
        int nbig = 0;
        const void *w_ = nullptr, *s_ = nullptr;
        for (int i = 0; i < n_in; ++i) {
            if (in_sizes[i] == DIM * 2) w_ = d_in[i];
            else if (in_sizes[i] == BATCH * SEQ) s_ = d_in[i];
            else if (in_sizes[i] == SEQ * DIM && nbig < 2) big[nbig++] = d_in[i];
        }
        if (w_ && s_ && nbig == 2) { wp = w_; sp = s_; xp = big[0]; pp = big[1]; }
    }

    fused_kernel<<<BATCH * PB, TPB, 0, stream>>>(
        (const float2*)xp, (const float4*)wp, (const float4*)pp,
        (const int*)sp, (float*)d_out);
}